// Round 8
// baseline (106.103 us; speedup 1.0000x reference)
//
#include <hip/hip_runtime.h>
#include <math.h>

#define Bn 32
#define Rn 512
#define Dn 256
#define Pn 5532
#define MAXU 512

#define TRr 32
#define TCc 128
#define KCs 64
#define NBLK ((Rn / TRr) * Bn)                        // 512 blocks in k3

// ---- workspace layout (4-byte words). nll+tick zeroed by k1 block 0 each
// call; everything else read-after-write in-call (poison-safe: pbf rows >= U
// are loaded but value-gated, proven benign R0-R7).
#define PBF_OFF    0
#define PBF_WORDS  (Bn*MAXU*Dn/2)
#define LBLC_OFF   (PBF_OFF + PBF_WORDS)
#define CCNT_OFF   (LBLC_OFF + Bn*Rn)
#define CURS_OFF   (CCNT_OFF + Bn*MAXU)               // END offsets
#define RLIST_OFF  (CURS_OFF + Bn*MAXU)
#define NUNIQ_OFF  (RLIST_OFF + Bn*Rn)
#define NVALID_OFF (NUNIQ_OFF + 32)
#define NLL_OFF    (NVALID_OFF + 32)
#define TICK_OFF   (NLL_OFF + 1)

typedef short short8 __attribute__((ext_vector_type(8)));
typedef short short4v __attribute__((ext_vector_type(4)));
typedef float floatx4 __attribute__((ext_vector_type(4)));

__device__ __forceinline__ unsigned short bf16r(float f) {   // fp32 -> bf16 RNE
    union { float f; unsigned int u; } c; c.f = f;
    return (unsigned short)((c.u + 0x7FFFu + ((c.u >> 16) & 1u)) >> 16);
}
__device__ __forceinline__ float bfu2f(unsigned int hi16) {  // <<16'd bf16 -> f32
    union { unsigned int u; float f; } c; c.u = hi16;
    return c.f;
}

// ==== k1: per-image compact via FIRST-TOUCH slot claim (R3/R4-proven scheme:
// no Pn-wide prefix scan — only a single 512-slot scan). blockIdx.x = b ->
// XCD = b%8, matching k2/k3's pinning. ====
__global__ __launch_bounds__(1024) void k1_compact(
    const int* __restrict__ roi_label,
    int* __restrict__ lblc_arr, int* __restrict__ ccnt, int* __restrict__ cursor,
    int* __restrict__ rlist, int* __restrict__ nuniq, int* __restrict__ nvalid_arr,
    int* __restrict__ zwords)
{
    __shared__ int cnt_l[Pn];                         // per-label counts
    __shared__ int slot_l[Pn];                        // first-touch slot; valid where cnt>0
    __shared__ int scnt[MAXU];                        // per-slot counts
    __shared__ int scur[MAXU];                        // start -> end cursors
    __shared__ int wtot[16];                          // per-wave scan totals
    __shared__ int uctr;

    const int b = blockIdx.x;
    const int t = threadIdx.x;
    const int lane = t & 63, wid = t >> 6;            // 16 waves

    if (b == 0 && t == 0) { zwords[0] = 0; zwords[1] = 0; }   // nll, tick

    for (int i = t; i < Pn; i += 1024) cnt_l[i] = 0;
    if (t < MAXU) scnt[t] = 0;
    if (t == 0) uctr = 0;
    __syncthreads();

    int l = -1;
    if (t < Rn) {
        l = roi_label[b * Rn + t] - 1;
        if (l >= 0) {
            if (atomicAdd(&cnt_l[l], 1) == 0)         // first toucher claims slot
                slot_l[l] = atomicAdd(&uctr, 1);
        }
    }
    __syncthreads();
    int lc = -1;
    if (t < Rn) {
        lc = (l >= 0) ? slot_l[l] : -1;
        lblc_arr[b * Rn + t] = lc;
        if (lc >= 0) atomicAdd(&scnt[lc], 1);
    }
    __syncthreads();
    const int U = uctr;

    // exclusive prefix over scnt[0..511]: waves 0..7 carry data, 8..15 zeros
    int v = (t < MAXU) ? scnt[t] : 0;
    int vs = v;
    #pragma unroll
    for (int off = 1; off < 64; off <<= 1) {
        int u = __shfl_up(vs, off);
        if (lane >= off) vs += u;
    }
    if (lane == 63) wtot[wid] = vs;
    __syncthreads();
    int woff = 0, tot = 0;
    #pragma unroll
    for (int w = 0; w < 16; ++w) {
        int c = wtot[w];
        if (w < wid) woff += c;
        tot += c;
    }
    if (t < MAXU) scur[t] = woff + vs - v;            // start offset
    __syncthreads();

    if (t < Rn && lc >= 0) {                          // scatter roi ids by slot
        int pos = atomicAdd(&scur[lc], 1);
        rlist[b * Rn + pos] = t;
    }
    __syncthreads();
    if (t < MAXU && t < U) {
        ccnt[b * MAXU + t]   = scnt[t];
        cursor[b * MAXU + t] = scur[t];               // END offset (= start + cnt)
    }
    if (t == 0) { nuniq[b] = U; nvalid_arr[b] = tot; }
}

// ==== k2: gather f32 inputs (bf16 round-trip, bit-identical) -> mean ->
// L2 normalize -> bf16 proto. One slot per WAVE, 4096 blocks, XCD-pinned
// (R7-proven verbatim). ====
__global__ __launch_bounds__(256) void k2_proto(
    const float* __restrict__ inputs, const float* __restrict__ cls,
    const int* __restrict__ nuniq, const int* __restrict__ ccnt,
    const int* __restrict__ cursor, const int* __restrict__ rlist,
    unsigned short* __restrict__ pbf)
{
    const int lane = threadIdx.x & 63, wv = threadIdx.x >> 6;
    const int h = blockIdx.x;                         // [0,4096)
    const int xcd = h & 7, widx = h >> 3;             // widx in [0,512)
    const int b = xcd + 8 * (widx >> 7);              // image pinned to XCD b%8
    const int inner = widx & 127;                     // [0,128) blocks per image
    int c = inner * 4 + wv;                           // slot within image
    int s = b * MAXU + c;
    if (c >= nuniq[b]) return;                        // wave-uniform exit
    int cnt = ccnt[s];
    int start = cursor[s] - cnt;
    float a0 = 0.f, a1 = 0.f, a2 = 0.f, a3 = 0.f;
    for (int k = 0; k < cnt; ++k) {
        int row = b * Rn + rlist[b * Rn + start + k];
        float cw = cls[row];
        float4 v = *(const float4*)&inputs[(size_t)row * Dn + lane * 4];
        // bf16 round-trip: bit-identical to the proven xbf path
        a0 += bfu2f(((unsigned)bf16r(v.x * cw)) << 16);
        a1 += bfu2f(((unsigned)bf16r(v.y * cw)) << 16);
        a2 += bfu2f(((unsigned)bf16r(v.z * cw)) << 16);
        a3 += bfu2f(((unsigned)bf16r(v.w * cw)) << 16);
    }
    float inv = 1.0f / (float)cnt;
    a0 *= inv; a1 *= inv; a2 *= inv; a3 *= inv;
    float ss = a0*a0 + a1*a1 + a2*a2 + a3*a3;
    #pragma unroll
    for (int off = 32; off > 0; off >>= 1) ss += __shfl_xor(ss, off);
    float sc = 1.0f / fmaxf(sqrtf(ss), 1e-12f);
    short4v o;
    o[0] = (short)bf16r(a0 * sc); o[1] = (short)bf16r(a1 * sc);
    o[2] = (short)bf16r(a2 * sc); o[3] = (short)bf16r(a3 * sc);
    *(short4v*)&pbf[(size_t)s * Dn + lane * 4] = o;
}

// ==== k3: 32 rois x ALL proto cols per block. B-fragments load GLOBAL->VGPR
// directly: wave w only ever reads ps rows [w*32,w*32+32) — zero cross-wave
// reuse, so the old LDS dbuf + 32 barriers/block were pure overhead. The pc
// loop is now barrier-free; same logical B elements and MFMA accumulate
// order as the R4-R7 proven kernel (bit-identical acc). XCD-pinned decode. ====
__global__ __launch_bounds__(256, 2) void k3_loss(
    const float* __restrict__ inputs, const float* __restrict__ cls,
    const unsigned short* __restrict__ pbf,
    const int* __restrict__ lblc_arr, const int* __restrict__ nuniq,
    const int* __restrict__ nvalid_arr,
    float* __restrict__ nll, int* __restrict__ tick, float* __restrict__ out)
{
    __shared__ __align__(16) unsigned short xs[TRr * Dn];      // 16 KB
    __shared__ int lblc[TRr];
    __shared__ float es_l[4][TRr];
    __shared__ float ds_l[4][TRr];

    const int t = threadIdx.x;
    const int lane = t & 63, w = t >> 6;
    const int q = lane >> 4, r15 = lane & 15;
    const int h = blockIdx.x;                         // [0,512)
    const int xcd = h & 7, widx = h >> 3;             // widx in [0,64)
    const int b  = xcd + 8 * (widx >> 4);             // image pinned to XCD b%8
    const int rt = widx & 15;
    const int roiBase = rt * TRr;
    const int U = nuniq[b];
    const int nch = (U <= 0) ? 1 : ((U + TCc - 1) >> 7);

    if (t < TRr) lblc[t] = lblc_arr[b * Rn + roiBase + t];

    // A-tile: f32 -> bf16 (bit-identical) -> swizzled LDS (gpos = g ^ (row&7))
    {
        const int row = t >> 3, seg = t & 7;          // 8 threads per roi row
        const size_t gbase = (size_t)(b * Rn + roiBase + row) * Dn + seg * 32;
        const float cw = cls[b * Rn + roiBase + row];
        #pragma unroll
        for (int jj = 0; jj < 4; ++jj) {
            float4 v0 = *(const float4*)&inputs[gbase + jj * 8];
            float4 v1 = *(const float4*)&inputs[gbase + jj * 8 + 4];
            short8 o;
            o[0] = (short)bf16r(v0.x * cw); o[1] = (short)bf16r(v0.y * cw);
            o[2] = (short)bf16r(v0.z * cw); o[3] = (short)bf16r(v0.w * cw);
            o[4] = (short)bf16r(v1.x * cw); o[5] = (short)bf16r(v1.y * cw);
            o[6] = (short)bf16r(v1.z * cw); o[7] = (short)bf16r(v1.w * cw);
            int gpos = (seg * 4 + jj) ^ (row & 7);
            *(short8*)&xs[row * Dn + gpos * 8] = o;
        }
    }
    __syncthreads();                                  // xs resident

    // preload all A fragments into registers: 64 VGPRs
    short8 areg[2][8];
    #pragma unroll
    for (int mt = 0; mt < 2; ++mt)
        #pragma unroll
        for (int kcs = 0; kcs < 8; ++kcs) {
            int row = mt * 16 + r15;
            int gpos = (kcs * 4 + q) ^ (row & 7);
            areg[mt][kcs] = *(const short8*)&xs[row * Dn + gpos * 8];
        }

    int lcr[2][4];
    float esum[2][4], dsum[2][4];
    #pragma unroll
    for (int mt = 0; mt < 2; ++mt)
        #pragma unroll
        for (int reg = 0; reg < 4; ++reg) {
            lcr[mt][reg] = lblc[mt * 16 + q * 4 + reg];
            esum[mt][reg] = 0.f; dsum[mt][reg] = 0.f;
        }

    // per-lane B row base: row = b*MAXU + pc*128 + w*32 + nt*16 + r15,
    // elems [st*64 + (kk*4+q)*8, +8) — q*8 folded into the base pointer.
    const unsigned short* pw0 =
        pbf + (size_t)(b * MAXU + w * 32 + r15) * Dn + q * 8;

    for (int pc = 0; pc < nch; ++pc) {
        const unsigned short* p0 = pw0 + (size_t)pc * TCc * Dn;   // nt = 0
        const unsigned short* p1 = p0 + 16 * Dn;                  // nt = 1
        short8 b0[8], b1[8];
        #pragma unroll
        for (int st = 0; st < 4; ++st)
            #pragma unroll
            for (int kk = 0; kk < 2; ++kk) {
                int off = st * KCs + kk * 32;         // elements
                b0[st * 2 + kk] = *(const short8*)&p0[off];
                b1[st * 2 + kk] = *(const short8*)&p1[off];
            }

        floatx4 acc[2][2];
        #pragma unroll
        for (int mt = 0; mt < 2; ++mt) {
            acc[mt][0] = (floatx4)0.f; acc[mt][1] = (floatx4)0.f;
        }
        #pragma unroll
        for (int f = 0; f < 8; ++f) {                 // same K order as before
            #pragma unroll
            for (int mt = 0; mt < 2; ++mt) {
                acc[mt][0] = __builtin_amdgcn_mfma_f32_16x16x32_bf16(
                    areg[mt][f], b0[f], acc[mt][0], 0, 0, 0);
                acc[mt][1] = __builtin_amdgcn_mfma_f32_16x16x32_bf16(
                    areg[mt][f], b1[f], acc[mt][1], 0, 0, 0);
            }
        }

        // per-pc epilogue in registers; C/D: n = r15, m = q*4 + reg
        #pragma unroll
        for (int nt = 0; nt < 2; ++nt) {
            int c = pc * TCc + w * 32 + nt * 16 + r15;
            bool v = c < U;
            #pragma unroll
            for (int mt = 0; mt < 2; ++mt)
                #pragma unroll
                for (int reg = 0; reg < 4; ++reg) {
                    float d = acc[mt][nt][reg];
                    if (v) esum[mt][reg] += __expf(d);
                    if (c == lcr[mt][reg]) dsum[mt][reg] += d;
                }
        }
    }

    // cross-lane (16) then cross-wave (LDS) combine; one atomic per block
    #pragma unroll
    for (int mt = 0; mt < 2; ++mt)
        #pragma unroll
        for (int reg = 0; reg < 4; ++reg) {
            float e = esum[mt][reg], d = dsum[mt][reg];
            #pragma unroll
            for (int off = 1; off < 16; off <<= 1) {
                e += __shfl_xor(e, off);
                d += __shfl_xor(d, off);
            }
            if (r15 == 0) {
                int row = mt * 16 + q * 4 + reg;
                es_l[w][row] = e;
                ds_l[w][row] = d;
            }
        }
    __syncthreads();
    if (t < TRr) {
        float es = es_l[0][t] + es_l[1][t] + es_l[2][t] + es_l[3][t];
        float ds = ds_l[0][t] + ds_l[1][t] + ds_l[2][t] + ds_l[3][t];
        float val = (lblc[t] >= 0) ? (__logf(es) - ds) : 0.f;
        #pragma unroll
        for (int off = 1; off < 32; off <<= 1) val += __shfl_xor(val, off);
        if (t == 0) {
            atomicAdd(nll, val);
            __threadfence();                          // order nll add vs ticket
            int old = atomicAdd(tick, 1);
            if (old == NBLK - 1) {                    // last block finalizes
                float total = atomicAdd(nll, 0.0f);   // coherent read
                int nv = 0;
                #pragma unroll
                for (int i = 0; i < Bn / 4; ++i) {
                    int4 vv = ((const int4*)nvalid_arr)[i];
                    nv += vv.x + vv.y + vv.z + vv.w;
                }
                out[0] = total / fmaxf((float)nv, 1.0f);
            }
        }
    }
}

extern "C" void kernel_launch(void* const* d_in, const int* in_sizes, int n_in,
                              void* d_out, int out_size, void* d_ws, size_t ws_size,
                              hipStream_t stream) {
    const float* inputs = (const float*)d_in[0];
    const float* cls    = (const float*)d_in[1];
    const int*   roi    = (const int*)d_in[2];
    int* wsi   = (int*)d_ws;
    float* out = (float*)d_out;

    unsigned short* pbf = (unsigned short*)(wsi + PBF_OFF);
    int*   lblc   = wsi + LBLC_OFF;
    int*   ccnt   = wsi + CCNT_OFF;
    int*   cursor = wsi + CURS_OFF;
    int*   rlist  = wsi + RLIST_OFF;
    int*   nuniq  = wsi + NUNIQ_OFF;
    int*   nvalid = wsi + NVALID_OFF;
    float* nll    = (float*)(wsi + NLL_OFF);
    int*   tick   = wsi + TICK_OFF;

    k1_compact<<<Bn, 1024, 0, stream>>>(roi, lblc, ccnt, cursor, rlist,
                                        nuniq, nvalid, wsi + NLL_OFF);
    k2_proto<<<(Bn * MAXU) / 4, 256, 0, stream>>>(inputs, cls, nuniq, ccnt,
                                                  cursor, rlist, pbf);
    k3_loss<<<NBLK, 256, 0, stream>>>(inputs, cls, pbf, lblc, nuniq, nvalid,
                                      nll, tick, out);
}